// Round 10
// baseline (916.367 us; speedup 1.0000x reference)
//
#include <hip/hip_runtime.h>
#include <math.h>

typedef unsigned short u16;
typedef unsigned int   u32;
typedef __attribute__((ext_vector_type(8))) short bf16x8;          // 8 bf16 = 4 VGPR (MFMA A/B frag)
typedef __attribute__((ext_vector_type(4))) float f32x4;           // MFMA C/D frag
typedef __attribute__((ext_vector_type(4))) unsigned short u16x4;

__device__ __forceinline__ float bf2f(u16 v){ return __uint_as_float(((u32)v) << 16); }
__device__ __forceinline__ u16 f2bf(float f){
  u32 u = __float_as_uint(f);
  return (u16)((u + 0x7fffu + ((u >> 16) & 1u)) >> 16);  // RNE
}
__device__ __forceinline__ float elu1(float x){ return x > 0.f ? x + 1.f : __expf(x); }
__device__ __forceinline__ float gelu_f(float v){
  float u = 0.7978845608f * (v + 0.044715f * v * v * v);
  float e = __expf(-2.f * fabsf(u));
  float th = copysignf((1.f - e) / (1.f + e), u);
  return 0.5f * v * (1.f + th);
}

// ---------------- cast f32 -> bf16, vectorized x4 ----------------
__global__ __launch_bounds__(256) void k_cast(const float* __restrict__ src, u16* __restrict__ dst, int n4){
  int i = blockIdx.x * 256 + threadIdx.x;
  int stride = gridDim.x * 256;
  for (; i < n4; i += stride){
    float4 v = ((const float4*)src)[i];
    u16x4 o; o.x = f2bf(v.x); o.y = f2bf(v.y); o.z = f2bf(v.z); o.w = f2bf(v.w);
    ((u16x4*)dst)[i] = o;
  }
}

// concat q_b,k_b,v_b -> one 3072-float bias
__global__ void k_cat3(const float* __restrict__ a, const float* __restrict__ b,
                       const float* __restrict__ c, float* __restrict__ dst){
  int i = blockIdx.x * 256 + threadIdx.x;
  dst[i] = i < 1024 ? a[i] : (i < 2048 ? b[i - 1024] : c[i - 2048]);
}

// ---------------- LayerNorm over C=1024: f32 in -> bf16 out ----------------
__global__ __launch_bounds__(256) void k_ln(const float* __restrict__ x, const float* __restrict__ w,
                                            const float* __restrict__ b, u16* __restrict__ out){
  const int t = threadIdx.x;
  const size_t m = blockIdx.x;
  float4 v = ((const float4*)(x + m * 1024))[t];
  float s  = v.x + v.y + v.z + v.w;
  float s2 = v.x*v.x + v.y*v.y + v.z*v.z + v.w*v.w;
  #pragma unroll
  for (int o = 32; o > 0; o >>= 1){ s += __shfl_down(s, o, 64); s2 += __shfl_down(s2, o, 64); }
  __shared__ float red[8];
  if ((t & 63) == 0){ red[t >> 6] = s; red[4 + (t >> 6)] = s2; }
  __syncthreads();
  s  = red[0] + red[1] + red[2] + red[3];
  s2 = red[4] + red[5] + red[6] + red[7];
  float mu  = s * (1.f / 1024.f);
  float inv = rsqrtf(s2 * (1.f / 1024.f) - mu * mu + 1e-5f);
  float4 wv = ((const float4*)w)[t];
  float4 bv = ((const float4*)b)[t];
  u16x4 o;
  o.x = f2bf((v.x - mu) * inv * wv.x + bv.x);
  o.y = f2bf((v.y - mu) * inv * wv.y + bv.y);
  o.z = f2bf((v.z - mu) * inv * wv.z + bv.z);
  o.w = f2bf((v.w - mu) * inv * wv.w + bv.w);
  ((u16x4*)(out + m * 1024))[t] = o;
}

// ---------------- per-token linear attention ----------------
__global__ __launch_bounds__(256) void k_attn(const u16* __restrict__ qkv, u16* __restrict__ out){
  __shared__ float qe[4][16][68];
  __shared__ float ke[4][16][68];
  __shared__ float sm[4][16][20];
  const int w = threadIdx.x >> 6, lane = threadIdx.x & 63;
  const size_t m = (size_t)blockIdx.x * 4 + w;
  const u16* base = qkv + m * 3072;
  #pragma unroll
  for (int i = 0; i < 8; ++i){
    int idx = i * 64 + lane;
    int h = idx >> 5, c2 = (idx & 31) * 2;
    u32 qv = ((const u32*)base)[idx];
    u32 kv = ((const u32*)base)[512 + idx];
    float2 qf, kf;
    qf.x = elu1(bf2f((u16)(qv & 0xffffu))); qf.y = elu1(bf2f((u16)(qv >> 16)));
    kf.x = elu1(bf2f((u16)(kv & 0xffffu))); kf.y = elu1(bf2f((u16)(kv >> 16)));
    *(float2*)&qe[w][h][c2] = qf;
    *(float2*)&ke[w][h][c2] = kf;
  }
  float vr[16];
  #pragma unroll
  for (int h = 0; h < 16; ++h) vr[h] = bf2f(base[2048 + h * 64 + lane]);
  __syncthreads();
  const int sh = lane >> 2, jb = lane & 3;
  float sacc[4] = {0.f, 0.f, 0.f, 0.f};
  #pragma unroll
  for (int d4 = 0; d4 < 16; ++d4){
    float4 q4 = *(const float4*)&qe[w][sh][d4 * 4];
    #pragma unroll
    for (int j = 0; j < 4; ++j){
      float4 k4 = *(const float4*)&ke[w][4 * jb + j][d4 * 4];
      sacc[j] += q4.x*k4.x + q4.y*k4.y + q4.z*k4.z + q4.w*k4.w;
    }
  }
  #pragma unroll
  for (int j = 0; j < 4; ++j) sm[w][sh][4 * jb + j] = sacc[j];
  float part = sacc[0] + sacc[1] + sacc[2] + sacc[3];
  part += __shfl_xor(part, 1, 64);
  part += __shfl_xor(part, 2, 64);
  if (jb == 0) sm[w][sh][16] = part;
  __syncthreads();
  float acc[16];
  #pragma unroll
  for (int h = 0; h < 16; ++h) acc[h] = 0.f;
  #pragma unroll
  for (int h = 0; h < 16; ++h){
    #pragma unroll
    for (int j4 = 0; j4 < 4; ++j4){
      float4 s4 = *(const float4*)&sm[w][h][j4 * 4];
      acc[h] += s4.x*vr[4*j4] + s4.y*vr[4*j4+1] + s4.z*vr[4*j4+2] + s4.w*vr[4*j4+3];
    }
  }
  u16* ob = out + m * 1024;
  #pragma unroll
  for (int h = 0; h < 16; ++h)
    ob[h * 64 + lane] = f2bf(acc[h] / sm[w][h][16]);
}

// ---------------- 128x128-tile 4-wave bf16 GEMM — m97 TLP structure, BK=64, 5 blocks/CU ----------------
// Single-buffered 32 KiB LDS; 5 x 32 KiB = exactly the 160 KiB pool, VGPR 60 <= 512/5.
// R10 single-variable change vs R9: __launch_bounds__(256,5) — one more resident block/CU of
// latency-hiding TLP (R9 verified mechanism: occupancy 21->40% gave FC 188->167 us).
// 128B rows carry the proven 0-conflict chunk-XOR swizzle (R2-R9: SQ_LDS_BANK_CONFLICT = 0).
// C = A(M,K) * W(N,K)^T + bias.  EPI 0: bf16 out  1: f32 = res + v  2: bf16 = gelu(v)  3: f32 += v
template<int EPI>
__global__ __launch_bounds__(256, 5) void k_gemm(const u16* __restrict__ A, const u16* __restrict__ W,
                                                 const float* __restrict__ bias, const float* __restrict__ res,
                                                 void* __restrict__ outp, int N, int K, int nbn){
  __shared__ alignas(16) char lds[32768];   // A [128][64]bf16 @0, B @16384
  const int tid  = threadIdx.x;
  const int lane = tid & 63, wid = tid >> 6;      // 4 waves: 2 (M) x 2 (N)
  const int wr = wid >> 1, wc = wid & 1;
  const int g = lane >> 4, l15 = lane & 15;
  // bijective XCD swizzle (all grids are multiples of 8)
  const int nwg = gridDim.x, bid = blockIdx.x;
  const int swz = (bid & 7) * (nwg >> 3) + (bid >> 3);
  const int m0 = (swz / nbn) * 128, n0 = (swz % nbn) * 128;
  const u16* gA = A + (size_t)m0 * K;
  const u16* gW = W + (size_t)n0 * K;
  const int nt = K >> 6;   // BK = 64

  f32x4 acc[4][4];
  #pragma unroll
  for (int i = 0; i < 4; ++i)
    #pragma unroll
    for (int j = 0; j < 4; ++j) acc[i][j] = (f32x4){0.f, 0.f, 0.f, 0.f};

  // loop-invariant stage offsets: li = i*256+tid covers row li>>3, phys chunk li&7;
  // global source chunk = (li&7)^(row&7) (inverse swizzle on the global side).
  size_t soff[4];
  #pragma unroll
  for (int i = 0; i < 4; ++i){
    int li = i * 256 + tid;
    int r  = li >> 3;
    soff[i] = (size_t)r * K + (size_t)(((li & 7) ^ (r & 7)) * 8);
  }
  // loop-invariant swizzled read bases: row = base64 + l15 (base64 multiple of 16),
  // so row&7 = l15&7; frag f adds 16 rows = +2048B, slice s flips chunk via (4s+g).
  char* const aB0 = lds + (wr * 64 + l15) * 128 + (((0 + g) ^ (l15 & 7)) << 4);
  char* const aB1 = lds + (wr * 64 + l15) * 128 + (((4 + g) ^ (l15 & 7)) << 4);
  char* const bB0 = lds + 16384 + (wc * 64 + l15) * 128 + (((0 + g) ^ (l15 & 7)) << 4);
  char* const bB1 = lds + 16384 + (wc * 64 + l15) * 128 + (((4 + g) ^ (l15 & 7)) << 4);

  for (int t = 0; t < nt; ++t){
    const u16* sA = gA + (t << 6);
    const u16* sW = gW + (t << 6);
    #pragma unroll
    for (int i = 0; i < 4; ++i){
      __builtin_amdgcn_global_load_lds((const __attribute__((address_space(1))) u32*)(sA + soff[i]),
                                       (__attribute__((address_space(3))) u32*)(lds + i * 4096 + wid * 1024), 16, 0, 0);
    }
    #pragma unroll
    for (int i = 0; i < 4; ++i){
      __builtin_amdgcn_global_load_lds((const __attribute__((address_space(1))) u32*)(sW + soff[i]),
                                       (__attribute__((address_space(3))) u32*)(lds + 16384 + i * 4096 + wid * 1024), 16, 0, 0);
    }
    __syncthreads();                 // drains vmcnt(0): tile landed

    // slice 0
    {
      bf16x8 a[4], b[4];
      #pragma unroll
      for (int f = 0; f < 4; ++f) a[f] = *(const bf16x8*)(aB0 + f * 2048);
      #pragma unroll
      for (int f = 0; f < 4; ++f) b[f] = *(const bf16x8*)(bB0 + f * 2048);
      #pragma unroll
      for (int mf = 0; mf < 4; ++mf)
        #pragma unroll
        for (int nf = 0; nf < 4; ++nf)
          acc[mf][nf] = __builtin_amdgcn_mfma_f32_16x16x32_bf16(a[mf], b[nf], acc[mf][nf], 0, 0, 0);
    }
    // slice 1
    {
      bf16x8 a[4], b[4];
      #pragma unroll
      for (int f = 0; f < 4; ++f) a[f] = *(const bf16x8*)(aB1 + f * 2048);
      #pragma unroll
      for (int f = 0; f < 4; ++f) b[f] = *(const bf16x8*)(bB1 + f * 2048);
      #pragma unroll
      for (int mf = 0; mf < 4; ++mf)
        #pragma unroll
        for (int nf = 0; nf < 4; ++nf)
          acc[mf][nf] = __builtin_amdgcn_mfma_f32_16x16x32_bf16(a[mf], b[nf], acc[mf][nf], 0, 0, 0);
    }
    __syncthreads();                 // all reads done before next stage overwrites
  }

  // epilogue: D frag col = lane&15, row = 4*(lane>>4) + r
  #pragma unroll
  for (int mf = 0; mf < 4; ++mf){
    #pragma unroll
    for (int nf = 0; nf < 4; ++nf){
      int row = m0 + wr * 64 + mf * 16 + 4 * g;
      int col = n0 + wc * 64 + nf * 16 + l15;
      float bcol = bias[col];
      #pragma unroll
      for (int r = 0; r < 4; ++r){
        float v = acc[mf][nf][r] + bcol;
        size_t idx = (size_t)(row + r) * N + col;
        if constexpr (EPI == 0){
          ((u16*)outp)[idx] = f2bf(v);
        } else if constexpr (EPI == 1){
          ((float*)outp)[idx] = res[idx] + v;
        } else if constexpr (EPI == 2){
          ((u16*)outp)[idx] = f2bf(gelu_f(v));
        } else {
          float* o = (float*)outp; o[idx] = o[idx] + v;
        }
      }
    }
  }
}

extern "C" void kernel_launch(void* const* d_in, const int* in_sizes, int n_in,
                              void* d_out, int out_size, void* d_ws, size_t ws_size,
                              hipStream_t stream){
  (void)in_sizes; (void)n_in; (void)out_size; (void)ws_size;
  const float* x    = (const float*)d_in[0];
  const float* ln1w = (const float*)d_in[1];
  const float* ln1b = (const float*)d_in[2];
  const float* qw   = (const float*)d_in[3];
  const float* qb   = (const float*)d_in[4];
  const float* kw   = (const float*)d_in[5];
  const float* kb   = (const float*)d_in[6];
  const float* vw   = (const float*)d_in[7];
  const float* vb   = (const float*)d_in[8];
  const float* ow   = (const float*)d_in[9];
  const float* ob   = (const float*)d_in[10];
  const float* ln2w = (const float*)d_in[11];
  const float* ln2b = (const float*)d_in[12];
  const float* fcw  = (const float*)d_in[13];
  const float* fcb  = (const float*)d_in[14];
  const float* pw   = (const float*)d_in[15];
  const float* pb   = (const float*)d_in[16];

  char* ws = (char*)d_ws;
  u16*   WQKV = (u16*)(ws + 0);              // [3072][1024] bf16 (q_w|k_w|v_w)
  u16*   WO   = (u16*)(ws + 6291456);        // [1024][1024]
  u16*   WFC  = (u16*)(ws + 8388608);        // [4096][1024]
  u16*   WPR  = (u16*)(ws + 16777216);       // [1024][4096]
  float* BQ   = (float*)(ws + 25165824);     // [3072]
  u16*   XN   = (u16*)(ws + 25178112);       // [16384][1024] bf16 (xn, reused for xn2)
  u16*   QKV  = (u16*)(ws + 58732544);       // [16384][3072] bf16
  u16*   ATT  = (u16*)(ws + 159395840);      // [16384][1024] bf16
  u16*   H    = QKV;                          // [16384][4096] bf16, reuses QKV+ATT region
  float* OUT  = (float*)d_out;               // x1 intermediate, then final output

  // weight casts (fp32 -> bf16)
  k_cast<<<512, 256, 0, stream>>>(qw, WQKV,           262144);
  k_cast<<<512, 256, 0, stream>>>(kw, WQKV + 1048576, 262144);
  k_cast<<<512, 256, 0, stream>>>(vw, WQKV + 2097152, 262144);
  k_cast<<<512, 256, 0, stream>>>(ow, WO,             262144);
  k_cast<<<1024, 256, 0, stream>>>(fcw, WFC,          1048576);
  k_cast<<<1024, 256, 0, stream>>>(pw,  WPR,          1048576);
  k_cat3<<<12, 256, 0, stream>>>(qb, kb, vb, BQ);

  // ln1 -> fused QKV gemm -> per-token attention -> O gemm (+x residual) -> OUT (x1)
  k_ln<<<16384, 256, 0, stream>>>(x, ln1w, ln1b, XN);
  k_gemm<0><<<128 * 24, 256, 0, stream>>>(XN, WQKV, BQ, nullptr, QKV, 3072, 1024, 24);
  k_attn<<<4096, 256, 0, stream>>>(QKV, ATT);
  k_gemm<1><<<128 * 8, 256, 0, stream>>>(ATT, WO, ob, x, OUT, 1024, 1024, 8);

  // ln2 -> FC gemm (+gelu) -> PROJ gemm (+x1 residual, in place on OUT)
  k_ln<<<16384, 256, 0, stream>>>(OUT, ln2w, ln2b, XN);
  k_gemm<2><<<128 * 32, 256, 0, stream>>>(XN, WFC, fcb, nullptr, H, 4096, 1024, 32);
  k_gemm<3><<<128 * 8, 256, 0, stream>>>(H, WPR, pb, nullptr, OUT, 1024, 4096, 8);
}

// Round 13
// 546.087 us; speedup vs baseline: 1.6781x; 1.6781x over previous
//
#include <hip/hip_runtime.h>
#include <math.h>

typedef unsigned short u16;
typedef unsigned int   u32;
typedef __attribute__((ext_vector_type(8))) short bf16x8;          // 8 bf16 = 4 VGPR (MFMA A/B frag)
typedef __attribute__((ext_vector_type(4))) float f32x4;           // MFMA C/D frag
typedef __attribute__((ext_vector_type(4))) unsigned short u16x4;

__device__ __forceinline__ float bf2f(u16 v){ return __uint_as_float(((u32)v) << 16); }
__device__ __forceinline__ u16 f2bf(float f){
  u32 u = __float_as_uint(f);
  return (u16)((u + 0x7fffu + ((u >> 16) & 1u)) >> 16);  // RNE
}
__device__ __forceinline__ float elu1(float x){ return x > 0.f ? x + 1.f : __expf(x); }
__device__ __forceinline__ float gelu_f(float v){
  float u = 0.7978845608f * (v + 0.044715f * v * v * v);
  float e = __expf(-2.f * fabsf(u));
  float th = copysignf((1.f - e) / (1.f + e), u);
  return 0.5f * v * (1.f + th);
}

// ---------------- one-shot prep: cast all 6 weight mats to bf16 + concat qkv bias ----------------
// float4 index ranges (TOTAL 3,145,728 = 12288 blocks x 256), sizes cross-checked vs R10 k_cast:
//   qw [0, 262144) | kw [262144, 524288) | vw [524288, 786432) | ow [786432, 1048576)
//     (each 262,144 float4 = 1024*1024 floats)
//   fcw [1048576, 2097152) | pw [2097152, 3145728)   (each 1,048,576 float4 = 4096*1024 floats)
__global__ __launch_bounds__(256) void k_prep(const float* __restrict__ qw, const float* __restrict__ kw,
                                              const float* __restrict__ vw, const float* __restrict__ ow,
                                              const float* __restrict__ fcw, const float* __restrict__ pw,
                                              const float* __restrict__ qb, const float* __restrict__ kb,
                                              const float* __restrict__ vb,
                                              u16* __restrict__ WQKV, u16* __restrict__ WO,
                                              u16* __restrict__ WFC, u16* __restrict__ WPR,
                                              float* __restrict__ BQ){
  int i = blockIdx.x * 256 + threadIdx.x;            // float4 index
  const float* src; u16* dst; int off;
  if (i < 1048576){
    if (i < 262144)     { src = qw; dst = WQKV;           off = i; }
    else if (i < 524288){ src = kw; dst = WQKV + 1048576; off = i - 262144; }
    else if (i < 786432){ src = vw; dst = WQKV + 2097152; off = i - 524288; }
    else                { src = ow; dst = WO;             off = i - 786432; }
  } else if (i < 2097152){ src = fcw; dst = WFC; off = i - 1048576; }
  else                   { src = pw;  dst = WPR; off = i - 2097152; }
  float4 v = ((const float4*)src)[off];
  u16x4 o; o.x = f2bf(v.x); o.y = f2bf(v.y); o.z = f2bf(v.z); o.w = f2bf(v.w);
  ((u16x4*)dst)[off] = o;
  // bias concat piggyback: first 3072 threads also write one BQ element
  if (i < 3072)
    BQ[i] = i < 1024 ? qb[i] : (i < 2048 ? kb[i - 1024] : vb[i - 2048]);
}

// ---------------- LayerNorm over C=1024: f32 in -> bf16 out ----------------
__global__ __launch_bounds__(256) void k_ln(const float* __restrict__ x, const float* __restrict__ w,
                                            const float* __restrict__ b, u16* __restrict__ out){
  const int t = threadIdx.x;
  const size_t m = blockIdx.x;
  float4 v = ((const float4*)(x + m * 1024))[t];
  float s  = v.x + v.y + v.z + v.w;
  float s2 = v.x*v.x + v.y*v.y + v.z*v.z + v.w*v.w;
  #pragma unroll
  for (int o = 32; o > 0; o >>= 1){ s += __shfl_down(s, o, 64); s2 += __shfl_down(s2, o, 64); }
  __shared__ float red[8];
  if ((t & 63) == 0){ red[t >> 6] = s; red[4 + (t >> 6)] = s2; }
  __syncthreads();
  s  = red[0] + red[1] + red[2] + red[3];
  s2 = red[4] + red[5] + red[6] + red[7];
  float mu  = s * (1.f / 1024.f);
  float inv = rsqrtf(s2 * (1.f / 1024.f) - mu * mu + 1e-5f);
  float4 wv = ((const float4*)w)[t];
  float4 bv = ((const float4*)b)[t];
  u16x4 o;
  o.x = f2bf((v.x - mu) * inv * wv.x + bv.x);
  o.y = f2bf((v.y - mu) * inv * wv.y + bv.y);
  o.z = f2bf((v.z - mu) * inv * wv.z + bv.z);
  o.w = f2bf((v.w - mu) * inv * wv.w + bv.w);
  ((u16x4*)(out + m * 1024))[t] = o;
}

// ---------------- per-token linear attention ----------------
__global__ __launch_bounds__(256) void k_attn(const u16* __restrict__ qkv, u16* __restrict__ out){
  __shared__ float qe[4][16][68];
  __shared__ float ke[4][16][68];
  __shared__ float sm[4][16][20];
  const int w = threadIdx.x >> 6, lane = threadIdx.x & 63;
  const size_t m = (size_t)blockIdx.x * 4 + w;
  const u16* base = qkv + m * 3072;
  #pragma unroll
  for (int i = 0; i < 8; ++i){
    int idx = i * 64 + lane;
    int h = idx >> 5, c2 = (idx & 31) * 2;
    u32 qv = ((const u32*)base)[idx];
    u32 kv = ((const u32*)base)[512 + idx];
    float2 qf, kf;
    qf.x = elu1(bf2f((u16)(qv & 0xffffu))); qf.y = elu1(bf2f((u16)(qv >> 16)));
    kf.x = elu1(bf2f((u16)(kv & 0xffffu))); kf.y = elu1(bf2f((u16)(kv >> 16)));
    *(float2*)&qe[w][h][c2] = qf;
    *(float2*)&ke[w][h][c2] = kf;
  }
  float vr[16];
  #pragma unroll
  for (int h = 0; h < 16; ++h) vr[h] = bf2f(base[2048 + h * 64 + lane]);
  __syncthreads();
  const int sh = lane >> 2, jb = lane & 3;
  float sacc[4] = {0.f, 0.f, 0.f, 0.f};
  #pragma unroll
  for (int d4 = 0; d4 < 16; ++d4){
    float4 q4 = *(const float4*)&qe[w][sh][d4 * 4];
    #pragma unroll
    for (int j = 0; j < 4; ++j){
      float4 k4 = *(const float4*)&ke[w][4 * jb + j][d4 * 4];
      sacc[j] += q4.x*k4.x + q4.y*k4.y + q4.z*k4.z + q4.w*k4.w;
    }
  }
  #pragma unroll
  for (int j = 0; j < 4; ++j) sm[w][sh][4 * jb + j] = sacc[j];
  float part = sacc[0] + sacc[1] + sacc[2] + sacc[3];
  part += __shfl_xor(part, 1, 64);
  part += __shfl_xor(part, 2, 64);
  if (jb == 0) sm[w][sh][16] = part;
  __syncthreads();
  float acc[16];
  #pragma unroll
  for (int h = 0; h < 16; ++h) acc[h] = 0.f;
  #pragma unroll
  for (int h = 0; h < 16; ++h){
    #pragma unroll
    for (int j4 = 0; j4 < 4; ++j4){
      float4 s4 = *(const float4*)&sm[w][h][j4 * 4];
      acc[h] += s4.x*vr[4*j4] + s4.y*vr[4*j4+1] + s4.z*vr[4*j4+2] + s4.w*vr[4*j4+3];
    }
  }
  u16* ob = out + m * 1024;
  #pragma unroll
  for (int h = 0; h < 16; ++h)
    ob[h * 64 + lane] = f2bf(acc[h] / sm[w][h][16]);
}

// ---------------- 128x128-tile 4-wave bf16 GEMM — m97 TLP structure + L2 supertiling ----------------
// R9 config (launch_bounds(256,4), 32 KiB LDS, proven 0-conflict swizzle) + block-order change:
// n-panels processed in groups of G=8; within a group blocks run n-fastest so the ~1024
// resident blocks share 8 B-panels (2 MB, L2-resident) and stream A once per group.
// C = A(M,K) * W(N,K)^T + bias.  EPI 0: bf16 out  1: f32 = res + v  2: bf16 = gelu(v)  3: f32 += v
template<int EPI>
__global__ __launch_bounds__(256, 4) void k_gemm(const u16* __restrict__ A, const u16* __restrict__ W,
                                                 const float* __restrict__ bias, const float* __restrict__ res,
                                                 void* __restrict__ outp, int N, int K, int nbn){
  __shared__ alignas(16) char lds[32768];   // A [128][64]bf16 @0, B @16384
  const int tid  = threadIdx.x;
  const int lane = tid & 63, wid = tid >> 6;      // 4 waves: 2 (M) x 2 (N)
  const int wr = wid >> 1, wc = wid & 1;
  const int g = lane >> 4, l15 = lane & 15;
  // XCD bijective swizzle, then supertile: group = 8 n-panels, n-fastest within group
  const int nwg = gridDim.x, bid = blockIdx.x;
  const int swz = (bid & 7) * (nwg >> 3) + (bid >> 3);
  const int gsz = (nwg / nbn) * 8;                // nbm * G
  const int grp = swz / gsz, gix = swz % gsz;
  const int m0 = (gix >> 3) * 128;
  const int n0 = (grp * 8 + (gix & 7)) * 128;
  const u16* gA = A + (size_t)m0 * K;
  const u16* gW = W + (size_t)n0 * K;
  const int nt = K >> 6;   // BK = 64

  f32x4 acc[4][4];
  #pragma unroll
  for (int i = 0; i < 4; ++i)
    #pragma unroll
    for (int j = 0; j < 4; ++j) acc[i][j] = (f32x4){0.f, 0.f, 0.f, 0.f};

  // loop-invariant stage offsets: li = i*256+tid covers row li>>3, phys chunk li&7;
  // global source chunk = (li&7)^(row&7) (inverse swizzle on the global side).
  size_t soff[4];
  #pragma unroll
  for (int i = 0; i < 4; ++i){
    int li = i * 256 + tid;
    int r  = li >> 3;
    soff[i] = (size_t)r * K + (size_t)(((li & 7) ^ (r & 7)) * 8);
  }
  // loop-invariant swizzled read bases: row = base64 + l15 (base64 multiple of 16),
  // so row&7 = l15&7; frag f adds 16 rows = +2048B, slice s flips chunk via (4s+g).
  char* const aB0 = lds + (wr * 64 + l15) * 128 + (((0 + g) ^ (l15 & 7)) << 4);
  char* const aB1 = lds + (wr * 64 + l15) * 128 + (((4 + g) ^ (l15 & 7)) << 4);
  char* const bB0 = lds + 16384 + (wc * 64 + l15) * 128 + (((0 + g) ^ (l15 & 7)) << 4);
  char* const bB1 = lds + 16384 + (wc * 64 + l15) * 128 + (((4 + g) ^ (l15 & 7)) << 4);

  for (int t = 0; t < nt; ++t){
    const u16* sA = gA + (t << 6);
    const u16* sW = gW + (t << 6);
    #pragma unroll
    for (int i = 0; i < 4; ++i){
      __builtin_amdgcn_global_load_lds((const __attribute__((address_space(1))) u32*)(sA + soff[i]),
                                       (__attribute__((address_space(3))) u32*)(lds + i * 4096 + wid * 1024), 16, 0, 0);
    }
    #pragma unroll
    for (int i = 0; i < 4; ++i){
      __builtin_amdgcn_global_load_lds((const __attribute__((address_space(1))) u32*)(sW + soff[i]),
                                       (__attribute__((address_space(3))) u32*)(lds + 16384 + i * 4096 + wid * 1024), 16, 0, 0);
    }
    __syncthreads();                 // drains vmcnt(0): tile landed

    // slice 0
    {
      bf16x8 a[4], b[4];
      #pragma unroll
      for (int f = 0; f < 4; ++f) a[f] = *(const bf16x8*)(aB0 + f * 2048);
      #pragma unroll
      for (int f = 0; f < 4; ++f) b[f] = *(const bf16x8*)(bB0 + f * 2048);
      #pragma unroll
      for (int mf = 0; mf < 4; ++mf)
        #pragma unroll
        for (int nf = 0; nf < 4; ++nf)
          acc[mf][nf] = __builtin_amdgcn_mfma_f32_16x16x32_bf16(a[mf], b[nf], acc[mf][nf], 0, 0, 0);
    }
    // slice 1
    {
      bf16x8 a[4], b[4];
      #pragma unroll
      for (int f = 0; f < 4; ++f) a[f] = *(const bf16x8*)(aB1 + f * 2048);
      #pragma unroll
      for (int f = 0; f < 4; ++f) b[f] = *(const bf16x8*)(bB1 + f * 2048);
      #pragma unroll
      for (int mf = 0; mf < 4; ++mf)
        #pragma unroll
        for (int nf = 0; nf < 4; ++nf)
          acc[mf][nf] = __builtin_amdgcn_mfma_f32_16x16x32_bf16(a[mf], b[nf], acc[mf][nf], 0, 0, 0);
    }
    __syncthreads();                 // all reads done before next stage overwrites
  }

  // epilogue: D frag col = lane&15, row = 4*(lane>>4) + r
  #pragma unroll
  for (int mf = 0; mf < 4; ++mf){
    #pragma unroll
    for (int nf = 0; nf < 4; ++nf){
      int row = m0 + wr * 64 + mf * 16 + 4 * g;
      int col = n0 + wc * 64 + nf * 16 + l15;
      float bcol = bias[col];
      #pragma unroll
      for (int r = 0; r < 4; ++r){
        float v = acc[mf][nf][r] + bcol;
        size_t idx = (size_t)(row + r) * N + col;
        if constexpr (EPI == 0){
          ((u16*)outp)[idx] = f2bf(v);
        } else if constexpr (EPI == 1){
          ((float*)outp)[idx] = res[idx] + v;
        } else if constexpr (EPI == 2){
          ((u16*)outp)[idx] = f2bf(gelu_f(v));
        } else {
          float* o = (float*)outp; o[idx] = o[idx] + v;
        }
      }
    }
  }
}

extern "C" void kernel_launch(void* const* d_in, const int* in_sizes, int n_in,
                              void* d_out, int out_size, void* d_ws, size_t ws_size,
                              hipStream_t stream){
  (void)in_sizes; (void)n_in; (void)out_size; (void)ws_size;
  const float* x    = (const float*)d_in[0];
  const float* ln1w = (const float*)d_in[1];
  const float* ln1b = (const float*)d_in[2];
  const float* qw   = (const float*)d_in[3];
  const float* qb   = (const float*)d_in[4];
  const float* kw   = (const float*)d_in[5];
  const float* kb   = (const float*)d_in[6];
  const float* vw   = (const float*)d_in[7];
  const float* vb   = (const float*)d_in[8];
  const float* ow   = (const float*)d_in[9];
  const float* ob   = (const float*)d_in[10];
  const float* ln2w = (const float*)d_in[11];
  const float* ln2b = (const float*)d_in[12];
  const float* fcw  = (const float*)d_in[13];
  const float* fcb  = (const float*)d_in[14];
  const float* pw   = (const float*)d_in[15];
  const float* pb   = (const float*)d_in[16];

  char* ws = (char*)d_ws;
  u16*   WQKV = (u16*)(ws + 0);              // [3072][1024] bf16 (q_w|k_w|v_w)
  u16*   WO   = (u16*)(ws + 6291456);        // [1024][1024]
  u16*   WFC  = (u16*)(ws + 8388608);        // [4096][1024]
  u16*   WPR  = (u16*)(ws + 16777216);       // [1024][4096]
  float* BQ   = (float*)(ws + 25165824);     // [3072]
  u16*   XN   = (u16*)(ws + 25178112);       // [16384][1024] bf16 (xn, reused for xn2)
  u16*   QKV  = (u16*)(ws + 58732544);       // [16384][3072] bf16
  u16*   ATT  = (u16*)(ws + 159395840);      // [16384][1024] bf16
  u16*   H    = QKV;                          // [16384][4096] bf16, reuses QKV+ATT region
  float* OUT  = (float*)d_out;               // x1 intermediate, then final output

  // one-shot weight casts + bias concat (3,145,728 float4 -> 12288 blocks)
  k_prep<<<12288, 256, 0, stream>>>(qw, kw, vw, ow, fcw, pw, qb, kb, vb, WQKV, WO, WFC, WPR, BQ);

  // ln1 -> fused QKV gemm -> per-token attention -> O gemm (+x residual) -> OUT (x1)
  k_ln<<<16384, 256, 0, stream>>>(x, ln1w, ln1b, XN);
  k_gemm<0><<<128 * 24, 256, 0, stream>>>(XN, WQKV, BQ, nullptr, QKV, 3072, 1024, 24);
  k_attn<<<4096, 256, 0, stream>>>(QKV, ATT);
  k_gemm<1><<<128 * 8, 256, 0, stream>>>(ATT, WO, ob, x, OUT, 1024, 1024, 8);

  // ln2 -> FC gemm (+gelu) -> PROJ gemm (+x1 residual, in place on OUT)
  k_ln<<<16384, 256, 0, stream>>>(OUT, ln2w, ln2b, XN);
  k_gemm<2><<<128 * 32, 256, 0, stream>>>(XN, WFC, fcb, nullptr, H, 4096, 1024, 32);
  k_gemm<3><<<128 * 8, 256, 0, stream>>>(H, WPR, pb, nullptr, OUT, 1024, 4096, 8);
}